// Round 8
// baseline (649.290 us; speedup 1.0000x reference)
//
#include <hip/hip_runtime.h>
#include <hip/hip_bf16.h>

#define E_EDGES 1000000

typedef __attribute__((ext_vector_type(8))) short bf16x8;
typedef __attribute__((ext_vector_type(4))) float f32x4;

#define WAITV(N) asm volatile("s_waitcnt vmcnt(" #N ")" ::: "memory")
#define BAR()    __builtin_amdgcn_s_barrier()

__device__ __forceinline__ short f2bf(float f) {
    union { __bf16 b; short s; } u;
    u.b = (__bf16)f;            // fptrunc -> v_cvt_pk_bf16_f32 fusion (RNE)
    return u.s;
}
__device__ __forceinline__ bf16x8 pack8(float4 a, float4 b) {
    bf16x8 r;
    r[0]=f2bf(a.x); r[1]=f2bf(a.y); r[2]=f2bf(a.z); r[3]=f2bf(a.w);
    r[4]=f2bf(b.x); r[5]=f2bf(b.y); r[6]=f2bf(b.z); r[7]=f2bf(b.w);
    return r;
}
__device__ __forceinline__ float4 ld4(const float* p) {
    return *reinterpret_cast<const float4*>(p);
}
__device__ __forceinline__ float silu1(float x) { return x / (1.f + __expf(-x)); }
__device__ __forceinline__ float tanh1(float x) {
    float e = __expf(2.f * x);
    return 1.f - 2.f / (e + 1.f);
}

// ---------------- weight pre-pack: f32 -> bf16 frags in CHUNK-LINEAR order ------
// 196 frags of 512 shorts; frag f element (l*8+j) = W[k(l,j)][n(l)].
//   frags 0..95   : W_in,  chunk cs=seg*4+ks (12 chunks), within: nt=0..7
//   frags 96..159 : W_time, chunk ch (8): ch<4 -> scale cols j=8+2ch+jj; else shift j=2(ch-4)+jj; within: jj*4+ks
//   frags 160..191: W1, chunk ch (4): nt=2ch+(sub>>2), ks=sub&3
//   frags 192..195: W2 padded, ks=0..3
__global__ void pack_weights_kernel(const float* __restrict__ Wt,
                                    const float* __restrict__ Win,
                                    const float* __restrict__ W1,
                                    const float* __restrict__ W2,
                                    short* __restrict__ ws)
{
    int gid = blockIdx.x * 256 + threadIdx.x;
    if (gid >= 196 * 512) return;
    int frag = gid >> 9, within = gid & 511;
    int l = within >> 3, j = within & 7;
    int lg = l >> 4, ln = l & 15;
    int krow = (lg << 3) + j;
    float v;
    if (frag < 96) {
        int cs = frag >> 3, nt = frag & 7;
        int seg = cs >> 2, ks = cs & 3;
        int k = seg * 128 + ks * 32 + krow;
        v = Win[k * 128 + nt * 16 + ln];
    } else if (frag < 160) {
        int t = frag - 96, ch = t >> 3, sub = t & 7;
        int jj = sub >> 2, ks = sub & 3;
        int jcol = (ch < 4) ? (8 + 2 * ch + jj) : (2 * (ch - 4) + jj);
        int k = ks * 32 + krow;
        v = Wt[k * 256 + jcol * 16 + ln];
    } else if (frag < 192) {
        int t = frag - 160, ch = t >> 3, sub = t & 7;
        int nt = 2 * ch + (sub >> 2), ks = sub & 3;
        int k = ks * 32 + krow;
        v = W1[k * 128 + nt * 16 + ln];
    } else {
        int ks = frag - 192;
        int k = ks * 32 + krow;
        v = (ln < 4) ? W2[k * 4 + ln] : 0.0f;
    }
    ws[gid] = f2bf(v);
}

__device__ __forceinline__ void stage_frag(const short* gsrc, short* ldst) {
    __builtin_amdgcn_global_load_lds(
        (const __attribute__((address_space(1))) void*)gsrc,
        (__attribute__((address_space(3))) void*)ldst, 16, 0, 0);
}

// ------ fused edge kernel: 4 waves x 16 edges; waves share staged weight chunks ------
__global__ __launch_bounds__(256, 3)
void edge_kernel(const float* __restrict__ h,
                 const float* __restrict__ pos,
                 const float* __restrict__ ea,
                 const float* __restrict__ dst_f,
                 const float* __restrict__ temb,
                 const float* __restrict__ adj,
                 const float* __restrict__ btime,
                 const float* __restrict__ bin,
                 const float* __restrict__ b1,
                 const float* __restrict__ cscale,
                 const int*   __restrict__ ei,
                 const short* __restrict__ ws,
                 float* __restrict__ out)
{
    __shared__ __align__(16) short Wb[2][4096];      // 2 x 8 KB shared weight chunk dbuf
    __shared__ __align__(16) short Tb[4][16 * 128];  // per-wave transpose buffer (16 KB total)

    const int tid = threadIdx.x;
    const int w   = tid >> 6;
    const int l   = tid & 63;
    const int ln  = l & 15;
    const int lg  = l >> 4;
    const int kb  = lg << 3;
    const int e0w = blockIdx.x * 64 + w * 16;
    const int em  = e0w + ln;                // this lane's edge (1 tile/wave)

    const int ir = ei[em];
    const int ic = ei[E_EDGES + em];

    // geometry raw loads NOW, math deferred to epilogue (no LDS, no divergence)
    const float px0 = pos[ir*3+0], py0 = pos[ir*3+1], pz0 = pos[ir*3+2];
    const float px1 = pos[ic*3+0], py1 = pos[ic*3+1], pz1 = pos[ic*3+2];
    const float a0  = adj[em*3+0], a1  = adj[em*3+1], a2  = adj[em*3+2];
    const float csc = cscale[0];

    // wave w stages frags {2w, 2w+1} of each 8-frag chunk
    #define STAGE8(p) { \
        const short* g_ = ws + (p) * 4096 + (w*2) * 512 + l * 8; \
        short* d_ = &Wb[(p) & 1][(w*2) * 512]; \
        stage_frag(g_, d_); \
        stage_frag(g_ + 512, d_ + 512); }
    #define STAGEW2() { \
        stage_frag(ws + 24 * 4096 + w * 512 + l * 8, &Wb[0][w * 512]); }

    // ---- prologue: seg0 A loads, then first weight chunk ----
    float4 Abuf[8];
    #pragma unroll
    for (int k2 = 0; k2 < 4; ++k2) {
        Abuf[2*k2]   = ld4(h + (long)ir * 128 + k2*32 + kb);
        Abuf[2*k2+1] = ld4(h + (long)ir * 128 + k2*32 + kb + 4);
    }
    STAGE8(0);

    f32x4 accX[8];
    #pragma unroll
    for (int i = 0; i < 8; ++i) accX[i] = (f32x4){0.f,0.f,0.f,0.f};
    bf16x8 af[4];

    // ---- X = h_input @ W_in : 12 shared chunks ----
    #pragma unroll
    for (int c = 0; c < 12; ++c) {
        if (c < 11) { STAGE8(c + 1); } else { STAGE8(12); }
        if (c == 1) {            // seg1: h[col]
            #pragma unroll
            for (int k2 = 0; k2 < 4; ++k2) {
                Abuf[2*k2]   = ld4(h + (long)ic * 128 + k2*32 + kb);
                Abuf[2*k2+1] = ld4(h + (long)ic * 128 + k2*32 + kb + 4);
            }
        }
        if (c == 5) {            // seg2: ea | dist
            #pragma unroll
            for (int k2 = 0; k2 < 4; ++k2) {
                const float* q = (k2 < 2) ? (ea    + (long)em*64 + k2*32 + kb)
                                          : (dst_f + (long)em*64 + (k2-2)*32 + kb);
                Abuf[2*k2]   = ld4(q);
                Abuf[2*k2+1] = ld4(q + 4);
            }
        }
        if (c == 9) {            // temb rows for T stage
            #pragma unroll
            for (int k2 = 0; k2 < 4; ++k2) {
                Abuf[2*k2]   = ld4(temb + (long)em * 128 + k2*32 + kb);
                Abuf[2*k2+1] = ld4(temb + (long)em * 128 + k2*32 + kb + 4);
            }
        }
        // ledger: 2 stage ops/chunk; 8-load A batches issued at c in {1,5,9}
        if (c == 1 || c == 2 || c == 5 || c == 6 || c == 9 || c == 10) { WAITV(10); }
        else { WAITV(2); }
        BAR();                                   // chunk c visible to all waves
        if (c == 0 || c == 4 || c == 8) {        // pack this seg's A fragments
            #pragma unroll
            for (int k2 = 0; k2 < 4; ++k2) af[k2] = pack8(Abuf[2*k2], Abuf[2*k2+1]);
        }
        {
            const int ks = c & 3;
            const short* wb = &Wb[c & 1][0];
            #pragma unroll
            for (int nt = 0; nt < 8; ++nt) {
                bf16x8 b = *reinterpret_cast<const bf16x8*>(&wb[nt*512 + l*8]);
                accX[nt] = __builtin_amdgcn_mfma_f32_16x16x32_bf16(af[ks], b, accX[nt], 0, 0, 0);
            }
        }
        BAR();                                   // buffer free for re-stage
    }

    // ---- bias + LayerNorm (row lives in a 16-lane quarter-group) ----
    #pragma unroll
    for (int nt = 0; nt < 8; ++nt) {
        float bv = bin[(nt<<4) + ln];
        #pragma unroll
        for (int r = 0; r < 4; ++r) accX[nt][r] += bv;
    }
    #pragma unroll
    for (int r = 0; r < 4; ++r) {
        float p = 0.f, q = 0.f;
        #pragma unroll
        for (int nt = 0; nt < 8; ++nt) { float x = accX[nt][r]; p += x; q += x*x; }
        #pragma unroll
        for (int d2 = 1; d2 < 16; d2 <<= 1) { p += __shfl_xor(p, d2); q += __shfl_xor(q, d2); }
        float mean = p * 0.0078125f;
        float var  = q * 0.0078125f - mean * mean;
        float rstd = rsqrtf(var + 1e-6f);
        #pragma unroll
        for (int nt = 0; nt < 8; ++nt)
            accX[nt][r] = (accX[nt][r] - mean) * rstd;
    }

    // ---- silu(temb) fragments from Abuf ----
    bf16x8 ttf[4];
    #pragma unroll
    for (int k2 = 0; k2 < 4; ++k2) {
        float4 va = Abuf[2*k2], vb = Abuf[2*k2+1];
        va.x=silu1(va.x); va.y=silu1(va.y); va.z=silu1(va.z); va.w=silu1(va.w);
        vb.x=silu1(vb.x); vb.y=silu1(vb.y); vb.z=silu1(vb.z); vb.w=silu1(vb.w);
        ttf[k2] = pack8(va, vb);
    }

    // ---- T stage: 8 shared chunks, FiLM inline ----
    #pragma unroll
    for (int t = 0; t < 8; ++t) {
        if (t < 7) { STAGE8(13 + t); } else { STAGE8(20); }
        WAITV(2);
        BAR();
        {
            const short* wb = &Wb[t & 1][0];     // (12+t)&1 == t&1
            #pragma unroll
            for (int jj = 0; jj < 2; ++jj) {
                f32x4 tt = (f32x4){0.f,0.f,0.f,0.f};
                #pragma unroll
                for (int ks = 0; ks < 4; ++ks) {
                    bf16x8 b = *reinterpret_cast<const bf16x8*>(&wb[(jj*4+ks)*512 + l*8]);
                    tt = __builtin_amdgcn_mfma_f32_16x16x32_bf16(ttf[ks], b, tt, 0, 0, 0);
                }
                if (t < 4) {
                    const int jx = 2*t + jj;
                    float bsc = btime[128 + (jx<<4) + ln];
                    #pragma unroll
                    for (int r = 0; r < 4; ++r) accX[jx][r] *= (1.f + tt[r] + bsc);
                } else {
                    const int jx = 2*(t-4) + jj;
                    float bsh = btime[(jx<<4) + ln];
                    #pragma unroll
                    for (int r = 0; r < 4; ++r) accX[jx][r] += tt[r] + bsh;
                }
            }
        }
        BAR();
    }

    // ---- transpose inv (C-layout -> A-layout) through per-wave LDS ----
    short* tbW = &Tb[w][0];
    #pragma unroll
    for (int nt = 0; nt < 8; ++nt)
        #pragma unroll
        for (int r = 0; r < 4; ++r)
            tbW[((lg<<2) + r)*128 + (nt<<4) + ln] = f2bf(accX[nt][r]);
    bf16x8 iaf[4];
    #pragma unroll
    for (int ks = 0; ks < 4; ++ks)
        iaf[ks] = *reinterpret_cast<const bf16x8*>(&tbW[ln*128 + (ks<<5) + kb]);

    // ---- W1 stage: 4 shared chunks ----
    f32x4 accY[8];
    #pragma unroll
    for (int i = 0; i < 8; ++i) accY[i] = (f32x4){0.f,0.f,0.f,0.f};
    #pragma unroll
    for (int u = 0; u < 4; ++u) {
        if (u < 3) { STAGE8(21 + u); WAITV(2); }
        else       { STAGEW2();      WAITV(1); }
        BAR();
        {
            const short* wb = &Wb[u & 1][0];     // (20+u)&1 == u&1
            #pragma unroll
            for (int s = 0; s < 2; ++s) {
                const int nt = 2*u + s;
                #pragma unroll
                for (int ks = 0; ks < 4; ++ks) {
                    bf16x8 b = *reinterpret_cast<const bf16x8*>(&wb[(s*4+ks)*512 + l*8]);
                    accY[nt] = __builtin_amdgcn_mfma_f32_16x16x32_bf16(iaf[ks], b, accY[nt], 0, 0, 0);
                }
            }
        }
        BAR();
    }

    // ---- silu + transpose back ----
    #pragma unroll
    for (int nt = 0; nt < 8; ++nt) {
        float bv = b1[(nt<<4) + ln];
        #pragma unroll
        for (int r = 0; r < 4; ++r)
            tbW[((lg<<2) + r)*128 + (nt<<4) + ln] = f2bf(silu1(accY[nt][r] + bv));
    }
    bf16x8 yaf[4];
    #pragma unroll
    for (int ks = 0; ks < 4; ++ks)
        yaf[ks] = *reinterpret_cast<const bf16x8*>(&tbW[ln*128 + (ks<<5) + kb]);

    // ---- W2 stage (chunk 24, Wb[0]) ----
    WAITV(0);
    BAR();
    f32x4 accZ = (f32x4){0.f,0.f,0.f,0.f};
    {
        const short* wb = &Wb[0][0];
        #pragma unroll
        for (int ks = 0; ks < 4; ++ks) {
            bf16x8 b = *reinterpret_cast<const bf16x8*>(&wb[ks*512 + l*8]);
            accZ = __builtin_amdgcn_mfma_f32_16x16x32_bf16(yaf[ks], b, accZ, 0, 0, 0);
        }
    }

    // ---- epilogue: geometry math + tanh + head-mean + atomic scatter ----
    {
        float dx = px0 - px1, dy = py0 - py1, dz = pz0 - pz1;
        float nrm = sqrtf(dx*dx + dy*dy + dz*dz);
        float sc  = csc / fmaxf(nrm, 1e-8f);
        float cdx = dx * sc, cdy = dy * sc, cdz = dz * sc;
        #pragma unroll
        for (int r = 0; r < 4; ++r) {
            const int m = (lg<<2) + r;           // edge within the wave tile
            float z  = tanh1(accZ[r]);
            float w0 = __shfl(a0, m), w1 = __shfl(a1, m), w2 = __shfl(a2, m);
            int   irm  = __shfl(ir, m);
            float cdxm = __shfl(cdx, m), cdym = __shfl(cdy, m), cdzm = __shfl(cdz, m);
            float wt = (ln == 0) ? 1.0f : (ln == 1 ? w0 : (ln == 2 ? w1 : (ln == 3 ? w2 : 0.0f)));
            float v = z * wt;
            v += __shfl_xor(v, 1);
            v += __shfl_xor(v, 2);               // heads 0..3 summed within 4-lane group
            float s = v * 0.25f;
            if (ln < 3) {
                float cdc = (ln == 0) ? cdxm : (ln == 1 ? cdym : cdzm);
                atomicAdd(&out[(long)irm*3 + ln], cdc * s);
            }
        }
    }
    #undef STAGE8
    #undef STAGEW2
}

extern "C" void kernel_launch(void* const* d_in, const int* in_sizes, int n_in,
                              void* d_out, int out_size, void* d_ws, size_t ws_size,
                              hipStream_t stream) {
    const float* h     = (const float*)d_in[0];
    const float* pos   = (const float*)d_in[1];
    const float* ea    = (const float*)d_in[2];
    const float* dist  = (const float*)d_in[3];
    const float* temb  = (const float*)d_in[4];
    const float* adj   = (const float*)d_in[5];
    const float* Wt    = (const float*)d_in[6];
    const float* bt    = (const float*)d_in[7];
    const float* Win   = (const float*)d_in[8];
    const float* bin   = (const float*)d_in[9];
    const float* W1    = (const float*)d_in[10];
    const float* b1    = (const float*)d_in[11];
    const float* W2    = (const float*)d_in[12];
    const float* cs    = (const float*)d_in[13];
    const int*   ei    = (const int*)d_in[14];
    float*       out   = (float*)d_out;
    short*       ws    = (short*)d_ws;

    pack_weights_kernel<<<(196*512 + 255) / 256, 256, 0, stream>>>(Wt, Win, W1, W2, ws);
    hipMemcpyAsync(out, pos, (size_t)out_size * sizeof(float),
                   hipMemcpyDeviceToDevice, stream);
    edge_kernel<<<E_EDGES / 64, 256, 0, stream>>>(h, pos, ea, dist, temb, adj,
                                                  bt, bin, b1, cs, ei, ws, out);
}

// Round 9
// 619.474 us; speedup vs baseline: 1.0481x; 1.0481x over previous
//
#include <hip/hip_runtime.h>
#include <hip/hip_bf16.h>

#define E_EDGES 1000000

typedef __attribute__((ext_vector_type(8))) short bf16x8;
typedef __attribute__((ext_vector_type(4))) float f32x4;

#define WAITV(N) asm volatile("s_waitcnt vmcnt(" #N ")" ::: "memory")
#define BAR()    __builtin_amdgcn_s_barrier()

__device__ __forceinline__ short f2bf(float f) {
    union { __bf16 b; short s; } u;
    u.b = (__bf16)f;
    return u.s;
}
__device__ __forceinline__ bf16x8 pack8(float4 a, float4 b) {
    bf16x8 r;
    r[0]=f2bf(a.x); r[1]=f2bf(a.y); r[2]=f2bf(a.z); r[3]=f2bf(a.w);
    r[4]=f2bf(b.x); r[5]=f2bf(b.y); r[6]=f2bf(b.z); r[7]=f2bf(b.w);
    return r;
}
__device__ __forceinline__ float4 ld4(const float* p) {
    return *reinterpret_cast<const float4*>(p);
}
__device__ __forceinline__ float silu1(float x) { return x / (1.f + __expf(-x)); }
__device__ __forceinline__ float tanh1(float x) {
    float e = __expf(2.f * x);
    return 1.f - 2.f / (e + 1.f);
}

// ---------------- weight pre-pack: f32 -> bf16 frags in CHUNK-LINEAR order ------
// 196 frags of 512 shorts; frag f element (l*8+j) = W[k(l,j)][n(l)].
//   frags 0..95   : W_in,  chunk cs=seg*4+ks (12 chunks), within: nt=0..7
//   frags 96..159 : W_time, chunk ch (8): ch<4 -> scale cols j=8+2ch+jj; else shift j=2(ch-4)+jj; within: jj*4+ks
//   frags 160..191: W1, chunk ch (4): nt=2ch+(sub>>2), ks=sub&3
//   frags 192..195: W2 padded, ks=0..3
__global__ void pack_weights_kernel(const float* __restrict__ Wt,
                                    const float* __restrict__ Win,
                                    const float* __restrict__ W1,
                                    const float* __restrict__ W2,
                                    short* __restrict__ ws)
{
    int gid = blockIdx.x * 256 + threadIdx.x;
    if (gid >= 196 * 512) return;
    int frag = gid >> 9, within = gid & 511;
    int l = within >> 3, j = within & 7;
    int lg = l >> 4, ln = l & 15;
    int krow = (lg << 3) + j;
    float v;
    if (frag < 96) {
        int cs = frag >> 3, nt = frag & 7;
        int seg = cs >> 2, ks = cs & 3;
        int k = seg * 128 + ks * 32 + krow;
        v = Win[k * 128 + nt * 16 + ln];
    } else if (frag < 160) {
        int t = frag - 96, ch = t >> 3, sub = t & 7;
        int jj = sub >> 2, ks = sub & 3;
        int jcol = (ch < 4) ? (8 + 2 * ch + jj) : (2 * (ch - 4) + jj);
        int k = ks * 32 + krow;
        v = Wt[k * 256 + jcol * 16 + ln];
    } else if (frag < 192) {
        int t = frag - 160, ch = t >> 3, sub = t & 7;
        int nt = 2 * ch + (sub >> 2), ks = sub & 3;
        int k = ks * 32 + krow;
        v = W1[k * 128 + nt * 16 + ln];
    } else {
        int ks = frag - 192;
        int k = ks * 32 + krow;
        v = (ln < 4) ? W2[k * 4 + ln] : 0.0f;
    }
    ws[gid] = f2bf(v);
}

__device__ __forceinline__ void stage_frag(const short* gsrc, short* ldst) {
    __builtin_amdgcn_global_load_lds(
        (const __attribute__((address_space(1))) void*)gsrc,
        (__attribute__((address_space(3))) void*)ldst, 16, 0, 0);
}

// ------ fused edge kernel: 4 waves x 16 edges; depth-3 shared chunk rotation,
//        ONE barrier per chunk: [WAITV(c); BAR; stage(c+2); compute(c)] ------
__global__ __launch_bounds__(256, 3)
void edge_kernel(const float* __restrict__ h,
                 const float* __restrict__ pos,
                 const float* __restrict__ ea,
                 const float* __restrict__ dst_f,
                 const float* __restrict__ temb,
                 const float* __restrict__ adj,
                 const float* __restrict__ btime,
                 const float* __restrict__ bin,
                 const float* __restrict__ b1,
                 const float* __restrict__ cscale,
                 const int*   __restrict__ ei,
                 const short* __restrict__ ws,
                 float* __restrict__ out)
{
    __shared__ __align__(16) short Wb[3][4096];   // 3 x 8 KB rotating weight chunks
    __shared__ __align__(16) short Tb[4][1024];   // per-wave 16x64 half-transpose (2 KB each)

    const int tid = threadIdx.x;
    const int w   = tid >> 6;
    const int l   = tid & 63;
    const int ln  = l & 15;
    const int lg  = l >> 4;
    const int kb  = lg << 3;
    const int e0w = blockIdx.x * 64 + w * 16;
    const int em  = e0w + ln;                // this lane's edge (1 tile/wave)

    const int ir = ei[em];
    const int ic = ei[E_EDGES + em];

    // geometry raw loads (math deferred to epilogue)
    const float px0 = pos[ir*3+0], py0 = pos[ir*3+1], pz0 = pos[ir*3+2];
    const float px1 = pos[ic*3+0], py1 = pos[ic*3+1], pz1 = pos[ic*3+2];
    const float a0  = adj[em*3+0], a1  = adj[em*3+1], a2  = adj[em*3+2];
    const float csc = cscale[0];

    // bias preloads -> registers (keeps ALL later phases free of VMEM, so the
    // compiler never emits a pipeline-draining vmcnt wait mid-loop)
    float btsh[8], btsc[8], binr[8], b1r[8];
    #pragma unroll
    for (int j = 0; j < 8; ++j) {
        btsh[j] = btime[(j<<4) + ln];
        btsc[j] = btime[128 + (j<<4) + ln];
        binr[j] = bin[(j<<4) + ln];
        b1r[j]  = b1[(j<<4) + ln];
    }

    // wave w stages frags {2w, 2w+1} of each 8-frag chunk into buf p%3
    #define STAGE8(p) { \
        const short* g_ = ws + (p) * 4096 + (w*2) * 512 + l * 8; \
        short* d_ = &Wb[(p) % 3][(w*2) * 512]; \
        stage_frag(g_, d_); \
        stage_frag(g_ + 512, d_ + 512); }
    #define STAGEW2() { \
        stage_frag(ws + 24 * 4096 + w * 512 + l * 8, &Wb[0][w * 512]); }

    // ---- prologue: seg0 A loads, then chunks 0 and 1 ----
    float4 Abuf[8];
    #pragma unroll
    for (int k2 = 0; k2 < 4; ++k2) {
        Abuf[2*k2]   = ld4(h + (long)ir * 128 + k2*32 + kb);
        Abuf[2*k2+1] = ld4(h + (long)ir * 128 + k2*32 + kb + 4);
    }
    STAGE8(0);
    STAGE8(1);

    f32x4 accX[8];
    #pragma unroll
    for (int i = 0; i < 8; ++i) accX[i] = (f32x4){0.f,0.f,0.f,0.f};
    bf16x8 af[4];

    // ---- X = h_input @ W_in : chunks 0..11 ----
    #pragma unroll
    for (int c = 0; c < 12; ++c) {
        // ledger: stage(c+1) newest (2 ops); +8 A-loads when batch at c-1/c-2
        if (c == 2 || c == 3 || c == 6 || c == 7 || c == 10 || c == 11) { WAITV(10); }
        else { WAITV(2); }
        BAR();                                   // chunk c visible; buf (c+2)%3 free
        STAGE8(c + 2);                           // chunks 2..13
        if (c == 1) {            // seg1: h[col]
            #pragma unroll
            for (int k2 = 0; k2 < 4; ++k2) {
                Abuf[2*k2]   = ld4(h + (long)ic * 128 + k2*32 + kb);
                Abuf[2*k2+1] = ld4(h + (long)ic * 128 + k2*32 + kb + 4);
            }
        }
        if (c == 5) {            // seg2: ea | dist
            #pragma unroll
            for (int k2 = 0; k2 < 4; ++k2) {
                const float* q = (k2 < 2) ? (ea    + (long)em*64 + k2*32 + kb)
                                          : (dst_f + (long)em*64 + (k2-2)*32 + kb);
                Abuf[2*k2]   = ld4(q);
                Abuf[2*k2+1] = ld4(q + 4);
            }
        }
        if (c == 9) {            // temb rows for T stage
            #pragma unroll
            for (int k2 = 0; k2 < 4; ++k2) {
                Abuf[2*k2]   = ld4(temb + (long)em * 128 + k2*32 + kb);
                Abuf[2*k2+1] = ld4(temb + (long)em * 128 + k2*32 + kb + 4);
            }
        }
        if (c == 0 || c == 4 || c == 8) {        // pack this seg's A fragments
            #pragma unroll
            for (int k2 = 0; k2 < 4; ++k2) af[k2] = pack8(Abuf[2*k2], Abuf[2*k2+1]);
        }
        {
            const int ks = c & 3;
            const short* wb = &Wb[c % 3][0];
            #pragma unroll
            for (int nt = 0; nt < 8; ++nt) {
                bf16x8 b = *reinterpret_cast<const bf16x8*>(&wb[nt*512 + l*8]);
                accX[nt] = __builtin_amdgcn_mfma_f32_16x16x32_bf16(af[ks], b, accX[nt], 0, 0, 0);
            }
        }
    }

    // ---- bias + LayerNorm (register-only; chunks 12,13 in flight) ----
    #pragma unroll
    for (int nt = 0; nt < 8; ++nt) {
        #pragma unroll
        for (int r = 0; r < 4; ++r) accX[nt][r] += binr[nt];
    }
    #pragma unroll
    for (int r = 0; r < 4; ++r) {
        float p = 0.f, q = 0.f;
        #pragma unroll
        for (int nt = 0; nt < 8; ++nt) { float x = accX[nt][r]; p += x; q += x*x; }
        #pragma unroll
        for (int d2 = 1; d2 < 16; d2 <<= 1) { p += __shfl_xor(p, d2); q += __shfl_xor(q, d2); }
        float mean = p * 0.0078125f;
        float var  = q * 0.0078125f - mean * mean;
        float rstd = rsqrtf(var + 1e-6f);
        #pragma unroll
        for (int nt = 0; nt < 8; ++nt)
            accX[nt][r] = (accX[nt][r] - mean) * rstd;
    }

    // ---- silu(temb) fragments from Abuf ----
    bf16x8 ttf[4];
    #pragma unroll
    for (int k2 = 0; k2 < 4; ++k2) {
        float4 va = Abuf[2*k2], vb = Abuf[2*k2+1];
        va.x=silu1(va.x); va.y=silu1(va.y); va.z=silu1(va.z); va.w=silu1(va.w);
        vb.x=silu1(vb.x); vb.y=silu1(vb.y); vb.z=silu1(vb.z); vb.w=silu1(vb.w);
        ttf[k2] = pack8(va, vb);
    }

    // ---- T stage: chunks 12..19, FiLM inline (register biases only) ----
    #pragma unroll
    for (int t = 0; t < 8; ++t) {
        WAITV(2);
        BAR();
        STAGE8(14 + t);                          // chunks 14..21
        {
            const short* wb = &Wb[(12 + t) % 3][0];
            #pragma unroll
            for (int jj = 0; jj < 2; ++jj) {
                f32x4 tt = (f32x4){0.f,0.f,0.f,0.f};
                #pragma unroll
                for (int ks = 0; ks < 4; ++ks) {
                    bf16x8 b = *reinterpret_cast<const bf16x8*>(&wb[(jj*4+ks)*512 + l*8]);
                    tt = __builtin_amdgcn_mfma_f32_16x16x32_bf16(ttf[ks], b, tt, 0, 0, 0);
                }
                if (t < 4) {
                    const int jx = 2*t + jj;
                    #pragma unroll
                    for (int r = 0; r < 4; ++r) accX[jx][r] *= (1.f + tt[r] + btsc[jx]);
                } else {
                    const int jx = 2*(t-4) + jj;
                    #pragma unroll
                    for (int r = 0; r < 4; ++r) accX[jx][r] += tt[r] + btsh[jx];
                }
            }
        }
    }

    // ---- transpose inv -> A-layout, two 16x64 half-passes (wave-local Tb) ----
    short* tbW = &Tb[w][0];
    bf16x8 iaf[4];
    #pragma unroll
    for (int hp = 0; hp < 2; ++hp) {
        #pragma unroll
        for (int nt4 = 0; nt4 < 4; ++nt4) {
            const int nt = hp*4 + nt4;
            #pragma unroll
            for (int r = 0; r < 4; ++r)
                tbW[((lg<<2) + r)*64 + (nt4<<4) + ln] = f2bf(accX[nt][r]);
        }
        #pragma unroll
        for (int k2 = 0; k2 < 2; ++k2)
            iaf[hp*2 + k2] = *reinterpret_cast<const bf16x8*>(&tbW[ln*64 + (k2<<5) + kb]);
    }

    // ---- W1 stage: chunks 20..23 ----
    f32x4 accY[8];
    #pragma unroll
    for (int i = 0; i < 8; ++i) accY[i] = (f32x4){0.f,0.f,0.f,0.f};
    #pragma unroll
    for (int u = 0; u < 4; ++u) {
        if (u < 3) { WAITV(2); } else { WAITV(1); }
        BAR();
        if (u < 2)       { STAGE8(22 + u); }     // chunks 22, 23
        else if (u == 2) { STAGEW2(); }          // chunk 24 (1 op/wave)
        {
            const short* wb = &Wb[(20 + u) % 3][0];
            #pragma unroll
            for (int s = 0; s < 2; ++s) {
                const int nt = 2*u + s;
                #pragma unroll
                for (int ks = 0; ks < 4; ++ks) {
                    bf16x8 b = *reinterpret_cast<const bf16x8*>(&wb[(s*4+ks)*512 + l*8]);
                    accY[nt] = __builtin_amdgcn_mfma_f32_16x16x32_bf16(iaf[ks], b, accY[nt], 0, 0, 0);
                }
            }
        }
    }

    // ---- silu + transpose back (half-passes) ----
    bf16x8 yaf[4];
    #pragma unroll
    for (int hp = 0; hp < 2; ++hp) {
        #pragma unroll
        for (int nt4 = 0; nt4 < 4; ++nt4) {
            const int nt = hp*4 + nt4;
            #pragma unroll
            for (int r = 0; r < 4; ++r)
                tbW[((lg<<2) + r)*64 + (nt4<<4) + ln] = f2bf(silu1(accY[nt][r] + b1r[nt]));
        }
        #pragma unroll
        for (int k2 = 0; k2 < 2; ++k2)
            yaf[hp*2 + k2] = *reinterpret_cast<const bf16x8*>(&tbW[ln*64 + (k2<<5) + kb]);
    }

    // ---- W2 stage (chunk 24, buf 0) ----
    WAITV(0);
    BAR();
    f32x4 accZ = (f32x4){0.f,0.f,0.f,0.f};
    {
        const short* wb = &Wb[0][0];
        #pragma unroll
        for (int ks = 0; ks < 4; ++ks) {
            bf16x8 b = *reinterpret_cast<const bf16x8*>(&wb[ks*512 + l*8]);
            accZ = __builtin_amdgcn_mfma_f32_16x16x32_bf16(yaf[ks], b, accZ, 0, 0, 0);
        }
    }

    // ---- epilogue: geometry math + tanh + head-mean + atomic scatter ----
    {
        float dx = px0 - px1, dy = py0 - py1, dz = pz0 - pz1;
        float nrm = sqrtf(dx*dx + dy*dy + dz*dz);
        float sc  = csc / fmaxf(nrm, 1e-8f);
        float cdx = dx * sc, cdy = dy * sc, cdz = dz * sc;
        #pragma unroll
        for (int r = 0; r < 4; ++r) {
            const int m = (lg<<2) + r;           // edge within the wave tile
            float z  = tanh1(accZ[r]);
            float w0 = __shfl(a0, m), w1 = __shfl(a1, m), w2 = __shfl(a2, m);
            int   irm  = __shfl(ir, m);
            float cdxm = __shfl(cdx, m), cdym = __shfl(cdy, m), cdzm = __shfl(cdz, m);
            float wt = (ln == 0) ? 1.0f : (ln == 1 ? w0 : (ln == 2 ? w1 : (ln == 3 ? w2 : 0.0f)));
            float v = z * wt;
            v += __shfl_xor(v, 1);
            v += __shfl_xor(v, 2);               // heads 0..3 summed within 4-lane group
            float s = v * 0.25f;
            if (ln < 3) {
                float cdc = (ln == 0) ? cdxm : (ln == 1 ? cdym : cdzm);
                atomicAdd(&out[(long)irm*3 + ln], cdc * s);
            }
        }
    }
    #undef STAGE8
    #undef STAGEW2
}

extern "C" void kernel_launch(void* const* d_in, const int* in_sizes, int n_in,
                              void* d_out, int out_size, void* d_ws, size_t ws_size,
                              hipStream_t stream) {
    const float* h     = (const float*)d_in[0];
    const float* pos   = (const float*)d_in[1];
    const float* ea    = (const float*)d_in[2];
    const float* dist  = (const float*)d_in[3];
    const float* temb  = (const float*)d_in[4];
    const float* adj   = (const float*)d_in[5];
    const float* Wt    = (const float*)d_in[6];
    const float* bt    = (const float*)d_in[7];
    const float* Win   = (const float*)d_in[8];
    const float* bin   = (const float*)d_in[9];
    const float* W1    = (const float*)d_in[10];
    const float* b1    = (const float*)d_in[11];
    const float* W2    = (const float*)d_in[12];
    const float* cs    = (const float*)d_in[13];
    const int*   ei    = (const int*)d_in[14];
    float*       out   = (float*)d_out;
    short*       ws    = (short*)d_ws;

    pack_weights_kernel<<<(196*512 + 255) / 256, 256, 0, stream>>>(Wt, Win, W1, W2, ws);
    hipMemcpyAsync(out, pos, (size_t)out_size * sizeof(float),
                   hipMemcpyDeviceToDevice, stream);
    edge_kernel<<<E_EDGES / 64, 256, 0, stream>>>(h, pos, ea, dist, temb, adj,
                                                  bt, bin, b1, cs, ei, ws, out);
}